// Round 4
// baseline (157.438 us; speedup 1.0000x reference)
//
#include <hip/hip_runtime.h>

// B=262144 x C=101 fp32 -> 3 scalars.
//
// R9: R8 byte-for-byte (grid-stride, team-of-16 per row, 7 aligned scalar
// dword loads j = s+16k, all cross-lane via DPP on the VALU pipe) with ONE
// change: 1024 -> 2048 blocks and __launch_bounds__(256, 8).
// R8 post-mortem: replacing all 29 DS-pipe shuffles/group with DPP changed
// nothing (153.9 -> 154.9) -> instruction mix exonerated. total = fixed
// re-poison (~124us) + main (~30us vs 17us HBM floor). Remaining suspect:
// latency. At 1024 blocks = 4 waves/SIMD, each iteration is
// issue-8-loads -> ~600-900cyc HBM wait -> ~240cyc compute; 3 other waves
// cover only ~720cyc -> memory pipe idles every iteration. 2048 blocks =
// 8 waves/SIMD doubles cover. launch_bounds(256,8) caps VGPR at 64 so all
// 8 waves are resident (kernel needs ~40-50 VGPR; no spill expected).
// R7 tangled this lever with misaligned dwordx4 + chunked scheduling; here
// it is isolated.
//
// pen = sum_j max(e_j - e_{j+1}, 0) - e_t with e_j := 0 for j >= 101
// (zero-pad absorbs the +e_100 term; identity validated R4/R5).

#define NC 101
#define LAMBDA_W 1000.0

template <int CTRL>
__device__ __forceinline__ float dpp_mov(float v) {
    // bound_ctrl=true: out-of-row source lanes produce 0
    return __int_as_float(__builtin_amdgcn_update_dpp(
        0, __float_as_int(v), CTRL, 0xf, 0xf, true));
}

// sum of the 16-lane team (DPP row); total lands in lane 15 of each row
__device__ __forceinline__ float team_sum16(float v) {
    v += dpp_mov<0x111>(v);   // row_shr:1
    v += dpp_mov<0x112>(v);   // row_shr:2
    v += dpp_mov<0x114>(v);   // row_shr:4
    v += dpp_mov<0x118>(v);   // row_shr:8
    return v;
}

__global__ __launch_bounds__(256, 8)
void ucl_stream_kernel(const float* __restrict__ x,
                       const int* __restrict__ tgt,
                       float2* __restrict__ partial,
                       int ngroups)              // B/4 row-groups
{
    const int tid  = threadIdx.x;
    const int lane = tid & 63;
    const int s    = lane & 15;                  // slot within team
    const int gwave  = blockIdx.x * 4 + (tid >> 6);
    const int nwaves = gridDim.x * 4;

    const float fs = (float)s;
    float conc = 0.f, pens = 0.f;

    for (int g = gwave; g < ngroups; g += nwaves) {
        const int row = g * 4 + (lane >> 4);     // team's row
        const float* __restrict__ xr = x + (size_t)row * NC;
        const int t = tgt[row];                  // broadcast within team

        // ---- hoisted predicated loads, j = s + 16k (always 4B-aligned) ----
        float e[7];
#pragma unroll
        for (int k = 0; k < 7; ++k) {
            const int j = s + 16 * k;
            e[k] = (j < NC) ? xr[j] : 0.f;
        }
        // exp; force 0 (not exp(0)=1) on padded lanes
#pragma unroll
        for (int k = 0; k < 7; ++k) {
            const int j = s + 16 * k;
            float ee = __expf(e[k]);
            e[k] = (j < NC) ? ee : 0.f;
        }

        // ---- moments ----
        float S = 0.f, W = 0.f, Q = 0.f;
#pragma unroll
        for (int k = 0; k < 7; ++k) {
            const float fj = fs + (float)(16 * k);
            S += e[k];
            W = fmaf(e[k], fj, W);
            Q = fmaf(e[k], fj * fj, Q);
        }

        // ---- penalty: d_j = e_j - e_{j+1} (e_{101..} = 0), all on VALU ----
        float pen = 0.f;
#pragma unroll
        for (int k = 0; k < 7; ++k) {
            float n1 = dpp_mov<0x101>(e[k]);               // row_shl:1 -> e_{j+1}, 0 at s==15
            float nx = (k < 6) ? dpp_mov<0x11F>(e[k + 1])  // row_shr:15 -> lane15 gets lane0's e[k+1]
                               : 0.f;
            float en = (s == 15) ? nx : n1;
            float d  = e[k] - en;
            pen += fmaxf(d, 0.f);
            const int j = s + 16 * k;
            pen -= (j == t) ? e[k] : 0.f;                  // -e_t by owner
        }

        // ---- team reduce on the VALU pipe (zero DS ops) ----
        S   = team_sum16(S);
        W   = team_sum16(W);
        Q   = team_sum16(Q);
        pen = team_sum16(pen);

        if (s == 15) {                           // row total lives in lane 15
            float pred = W / S;
            float var  = fmaxf(fmaf(-pred, pred, Q / S), 1e-6f);
            float err  = pred - (float)t;
            conc += 0.5f * __logf(var) + err * err / (2.0f * var);
            pens += pen / S;
        }
    }

    // ---- wave reduce (values at lanes 15,31,47,63) ----
    conc += __shfl_down(conc, 16);
    pens += __shfl_down(pens, 16);
    conc += __shfl_down(conc, 32);
    pens += __shfl_down(pens, 32);

    __shared__ float red[8];
    if (lane == 15) {
        red[(tid >> 6) * 2 + 0] = conc;
        red[(tid >> 6) * 2 + 1] = pens;
    }
    __syncthreads();
    if (tid == 0)
        partial[blockIdx.x] = make_float2(red[0] + red[2] + red[4] + red[6],
                                          red[1] + red[3] + red[5] + red[7]);
}

__global__ __launch_bounds__(256)
void ucl_finalize(const float2* __restrict__ partial,
                  float* __restrict__ out,
                  int nblocks, double invB)
{
    const int tid = threadIdx.x;
    double c = 0.0, p = 0.0;
    for (int i = tid; i < nblocks; i += 256) {
        float2 v = partial[i];
        c += (double)v.x;
        p += (double)v.y;
    }
#pragma unroll
    for (int off = 32; off > 0; off >>= 1) {
        c += __shfl_down(c, off);
        p += __shfl_down(p, off);
    }
    __shared__ double sm[8];
    if ((tid & 63) == 0) { sm[(tid >> 6) * 2] = c; sm[(tid >> 6) * 2 + 1] = p; }
    __syncthreads();
    if (tid == 0) {
        double C = (sm[0] + sm[2] + sm[4] + sm[6]) * invB;
        double P = (sm[1] + sm[3] + sm[5] + sm[7]) * invB * LAMBDA_W;
        out[0] = (float)(C + P);
        out[1] = (float)C;
        out[2] = (float)P;
    }
}

extern "C" void kernel_launch(void* const* d_in, const int* in_sizes, int n_in,
                              void* d_out, int out_size, void* d_ws, size_t ws_size,
                              hipStream_t stream)
{
    const float* x   = (const float*)d_in[0];
    const int*   tgt = (const int*)d_in[1];
    float* out = (float*)d_out;
    float2* partial = (float2*)d_ws;

    const int B = in_sizes[1];        // 262144
    const int ngroups = B / 4;        // 65536
    const int blocks = 2048;          // 8 waves/SIMD (isolated lever vs R8)

    hipLaunchKernelGGL(ucl_stream_kernel, dim3(blocks), dim3(256), 0, stream,
                       x, tgt, partial, ngroups);
    hipLaunchKernelGGL(ucl_finalize, dim3(1), dim3(256), 0, stream,
                       partial, out, blocks, 1.0 / (double)B);
}

// Round 5
// 156.584 us; speedup vs baseline: 1.0055x; 1.0055x over previous
//
#include <hip/hip_runtime.h>

// B=262144 x C=101 fp32 -> 3 scalars.
//
// R10: request-size restructuring. R8 (DS->DPP) and R9 (4->8 waves/SIMD)
// were both neutral: main kernel pinned at ~30us = 3.5 TB/s regardless of
// instruction mix or occupancy. Remaining theory: the fabric is REQUEST-
// rate-limited (~54 Greq/s: fills = 6.8 TB/s at 128 B/req; us = 3.4 TB/s
// at 64 B/req). The old j=s+16k team loads touch 4 scattered 64 B runs per
// instruction -> sector requests. R10 keeps the team-of-16 compute EXACTLY
// (DPP reduce, penalty identity validated R4/R5/R8) but loads each 4-row
// group (1616 B) through a 256 B-aligned 2048 B LDS window:
//   * 2 x global_load_lds width=16: wave-contiguous 1 KB spans -> full
//     128 B line requests. Dest is lane-linear = the intrinsic's layout.
//   * targets: 1 exec-masked (lane 0) global_load_lds of 16 B (4 ints).
//   * redistribution: 8 ds_read_b32/lane (DS pipe proven free in R8;
//     ~2-4-way bank aliasing ~ free per m136).
//   * wave-local double buffer, counted s_waitcnt vmcnt(3) (3 ordered
//     gload intrinsics per iteration; never drained mid-loop; no barriers).
//   * window overlap (+432 B max) is re-read by the ADJACENT wave (same
//     block, same CU) -> L1/L2 hit, not HBM overfetch.
//   * last group (g=ngroups-1): clamped window breaks idx<512 bound ->
//     R6-style direct scalar loads for that one group (1 wave, 1 iter).
// Grid: 1024 blocks (R9 showed 2048 is not better), 4096 waves -> exactly
// 16 groups/wave.

#define NC 101
#define LAMBDA_W 1000.0
#define GRPB 1616u          // bytes per 4-row group
#define WINB 2048u          // aligned LDS window bytes
#define WINF 512            // window floats

typedef const void __attribute__((address_space(1)))* as1_cptr;
typedef void __attribute__((address_space(3)))* as3_ptr;

__device__ __forceinline__ void gload_lds16(const void* g, void* l) {
    // width must be a literal 16 -> global_load_lds_dwordx4
    // LDS dest = (uniform l) + lane*16; global src = per-lane g.
    __builtin_amdgcn_global_load_lds((as1_cptr)g, (as3_ptr)l, 16, 0, 0);
}

template <int CTRL>
__device__ __forceinline__ float dpp_mov(float v) {
    // bound_ctrl=true: out-of-row source lanes produce 0
    return __int_as_float(__builtin_amdgcn_update_dpp(
        0, __float_as_int(v), CTRL, 0xf, 0xf, true));
}

// sum of the 16-lane team (DPP row); total lands in lane 15 of each row
__device__ __forceinline__ float team_sum16(float v) {
    v += dpp_mov<0x111>(v);   // row_shr:1
    v += dpp_mov<0x112>(v);   // row_shr:2
    v += dpp_mov<0x114>(v);   // row_shr:4
    v += dpp_mov<0x118>(v);   // row_shr:8
    return v;
}

__global__ __launch_bounds__(256)
void ucl_stream_kernel(const float* __restrict__ x,
                       const int* __restrict__ tgt,
                       float2* __restrict__ partial,
                       int ngroups)              // B/4 row-groups
{
    const int tid  = threadIdx.x;
    const int lane = tid & 63;
    const int s    = lane & 15;                  // slot within team
    const int r    = lane >> 4;                  // team (row within group)
    const int wid  = tid >> 6;
    const int gwave  = blockIdx.x * 4 + wid;
    const int nwaves = gridDim.x * 4;

    // per wave: 2 buffers x (512 window floats + 4 tgt ints + pad)
    __shared__ float smem[4][2][528];
    const uint32_t total_b = (uint32_t)ngroups * GRPB;
    const char* xb = (const char*)x;

    const float fs = (float)s;
    float conc = 0.f, pens = 0.f;

    // prefetch group gn into buffer nb; returns float offset d of the
    // group start within the window (multiple of 4; <=60 except clamped tail)
    auto prefetch = [&](int gn, int nb) -> int {
        uint32_t start = (uint32_t)gn * GRPB;
        uint32_t base  = start & ~255u;
        if (base > total_b - WINB) base = total_b - WINB;   // only g=ngroups-1
        const char* src = xb + base + ((uint32_t)lane << 4);
        float* dst = &smem[wid][nb][0];
        gload_lds16(src, dst);                               // bytes [0,1024)
        gload_lds16(src + 1024, (char*)dst + 1024);          // bytes [1024,2048)
        if (lane == 0)                                       // 4 targets, 16 B
            gload_lds16((const char*)tgt + (uint32_t)gn * 16u,
                        (char*)dst + 2048);
        return (int)((start - base) >> 2);
    };

    int cur  = 0;
    int dcur = prefetch(gwave, 0);               // gwave < ngroups always

    for (int g = gwave; g < ngroups; g += nwaves) {
        const int gnext = g + nwaves;
        int dnext = 0;
        if (gnext < ngroups) {
            dnext = prefetch(gnext, cur ^ 1);    // 3 ordered VMEM in flight
            asm volatile("s_waitcnt vmcnt(3)" ::: "memory");  // cur buf ready
        } else {
            asm volatile("s_waitcnt vmcnt(0)" ::: "memory");  // final drain
        }

        const float* buf = &smem[wid][cur][0];
        const int t = ((const int*)(buf + WINF))[r];   // team's target (bcast)

        // ---- gather team layout j = s+16k from the window ----
        float e[7];
        if (g != ngroups - 1) {
            const int boff = dcur + 101 * r + s;
#pragma unroll
            for (int k = 0; k < 7; ++k) {
                const int j = s + 16 * k;
                float v  = buf[boff + 16 * k];   // garbage ok for j>=NC
                float ee = __expf(v);
                e[k] = (j < NC) ? ee : 0.f;      // select kills pad/garbage
            }
        } else {
            // clamped-window tail group: direct scalar loads (R6 path)
            const float* xr = x + (size_t)(g * 4 + r) * NC;
#pragma unroll
            for (int k = 0; k < 7; ++k) {
                const int j = s + 16 * k;
                float v  = (j < NC) ? xr[j] : 0.f;
                float ee = __expf(v);
                e[k] = (j < NC) ? ee : 0.f;
            }
        }

        // ---- moments ----
        float S = 0.f, W = 0.f, Q = 0.f;
#pragma unroll
        for (int k = 0; k < 7; ++k) {
            const float fj = fs + (float)(16 * k);
            S += e[k];
            W = fmaf(e[k], fj, W);
            Q = fmaf(e[k], fj * fj, Q);
        }

        // ---- penalty: d_j = e_j - e_{j+1} (e_{101..} = 0), all on VALU ----
        float pen = 0.f;
#pragma unroll
        for (int k = 0; k < 7; ++k) {
            float n1 = dpp_mov<0x101>(e[k]);               // row_shl:1 -> e_{j+1}, 0 at s==15
            float nx = (k < 6) ? dpp_mov<0x11F>(e[k + 1])  // row_shr:15 -> lane15 gets lane0's e[k+1]
                               : 0.f;
            float en = (s == 15) ? nx : n1;
            float d  = e[k] - en;
            pen += fmaxf(d, 0.f);
            const int j = s + 16 * k;
            pen -= (j == t) ? e[k] : 0.f;                  // -e_t by owner
        }

        // ---- team reduce on the VALU pipe ----
        S   = team_sum16(S);
        W   = team_sum16(W);
        Q   = team_sum16(Q);
        pen = team_sum16(pen);

        if (s == 15) {                           // row total lives in lane 15
            float pred = W / S;
            float var  = fmaxf(fmaf(-pred, pred, Q / S), 1e-6f);
            float err  = pred - (float)t;
            conc += 0.5f * __logf(var) + err * err / (2.0f * var);
            pens += pen / S;
        }

        cur ^= 1;
        dcur = dnext;
    }

    // ---- wave reduce (values at lanes 15,31,47,63) ----
    conc += __shfl_down(conc, 16);
    pens += __shfl_down(pens, 16);
    conc += __shfl_down(conc, 32);
    pens += __shfl_down(pens, 32);

    __shared__ float red[8];
    if (lane == 15) {
        red[wid * 2 + 0] = conc;
        red[wid * 2 + 1] = pens;
    }
    __syncthreads();
    if (tid == 0)
        partial[blockIdx.x] = make_float2(red[0] + red[2] + red[4] + red[6],
                                          red[1] + red[3] + red[5] + red[7]);
}

__global__ __launch_bounds__(256)
void ucl_finalize(const float2* __restrict__ partial,
                  float* __restrict__ out,
                  int nblocks, double invB)
{
    const int tid = threadIdx.x;
    double c = 0.0, p = 0.0;
    for (int i = tid; i < nblocks; i += 256) {
        float2 v = partial[i];
        c += (double)v.x;
        p += (double)v.y;
    }
#pragma unroll
    for (int off = 32; off > 0; off >>= 1) {
        c += __shfl_down(c, off);
        p += __shfl_down(p, off);
    }
    __shared__ double sm[8];
    if ((tid & 63) == 0) { sm[(tid >> 6) * 2] = c; sm[(tid >> 6) * 2 + 1] = p; }
    __syncthreads();
    if (tid == 0) {
        double C = (sm[0] + sm[2] + sm[4] + sm[6]) * invB;
        double P = (sm[1] + sm[3] + sm[5] + sm[7]) * invB * LAMBDA_W;
        out[0] = (float)(C + P);
        out[1] = (float)C;
        out[2] = (float)P;
    }
}

extern "C" void kernel_launch(void* const* d_in, const int* in_sizes, int n_in,
                              void* d_out, int out_size, void* d_ws, size_t ws_size,
                              hipStream_t stream)
{
    const float* x   = (const float*)d_in[0];
    const int*   tgt = (const int*)d_in[1];
    float* out = (float*)d_out;
    float2* partial = (float2*)d_ws;

    const int B = in_sizes[1];        // 262144
    const int ngroups = B / 4;        // 65536
    const int blocks = 1024;          // 4096 waves -> exactly 16 groups/wave

    hipLaunchKernelGGL(ucl_stream_kernel, dim3(blocks), dim3(256), 0, stream,
                       x, tgt, partial, ngroups);
    hipLaunchKernelGGL(ucl_finalize, dim3(1), dim3(256), 0, stream,
                       partial, out, blocks, 1.0 / (double)B);
}